// Round 8
// baseline (3588.572 us; speedup 1.0000x reference)
//
#include <hip/hip_runtime.h>
#include <hip/hip_bf16.h>
#include <hip/hip_fp16.h>

// Problem: S,B,E,H,V,O = 1024,256,128,256,32000,2
#define S_LEN 1024
#define BATCH 256
#define EDIM  128
#define HDIM  256
#define ODIM  2

typedef unsigned int uint32;
typedef unsigned long long uint64;
typedef _Float16 half_t;
typedef half_t half2v __attribute__((ext_vector_type(2)));
typedef half_t half8  __attribute__((ext_vector_type(8)));
typedef float  f32x4  __attribute__((ext_vector_type(4)));

// ---------------- ws layout (uint32 units) ----------------
// whhf: MFMA A-fragments of W_hh, [2 q][32 T][8 t][64 lane][4 dw]  (f16 pairs)
// wihf: MFMA A-fragments of W_ih, [2 q][32 T][4 t][64 lane][4 dw]
// hbuf: LL chunks: [2 par][16 c][16 b][128 pair-chunks] x {payload dw, seq dw}
//       Discovery slots embedded in hbuf (par=1, c, b=0, chunk=64q) — prep-zeroed,
//       not overwritten until end of step 1, which happens-after discovery.
#define OFF_WHHF   0
#define OFF_WIHF   131072
#define OFF_HBUF   196608
#define HBUF_DW    131072   // 65536 chunks * 2 dw

__device__ __forceinline__ float sigf(float x)     { return 1.0f / (1.0f + __expf(-x)); }
__device__ __forceinline__ float tanhfast(float x) { return 1.0f - 2.0f / (__expf(2.0f * x) + 1.0f); }

__device__ __forceinline__ uint32 packh2(float a, float b) {
  union { uint32 u; half2v h; } c; c.h[0] = (half_t)a; c.h[1] = (half_t)b; return c.u;
}
__device__ __forceinline__ half8 as_h8(uint4 v) {
  union { uint4 u; half8 h; } c; c.u = v; return c.h;
}

#define MFMA16(A, B, C) __builtin_amdgcn_mfma_f32_16x16x32_f16(as_h8(A), as_h8(B), (C), 0, 0, 0)

// ---------------- prep: pack W into per-lane MFMA A-fragment order ----------------
// A-layout (16x16x32): lane l holds A[m = l&15][k = (l>>4)*8 + j], j=0..7 (f16 pairs, 4 dw).
// 2-member split: member q owns units 128q..128q+127 (32 row-tiles: gate g = T>>3,
// unit sub-block T&7). grow(T,l) = (T>>3)*256 + q*128 + (T&7)*16 + (l&15).
__global__ void prep_kernel(const float* __restrict__ w_ih, const float* __restrict__ w_hh,
                            uint32* __restrict__ ws_u) {
  int id = blockIdx.x * 256 + threadIdx.x;
  if (id < 131072) {                     // whhf dwords: [q][T(32)][t(8)][l][d]
    int q = id >> 16, T = (id >> 11) & 31, t = (id >> 8) & 7, l = (id >> 2) & 63, d = id & 3;
    int grow = (T >> 3) * 256 + q * 128 + (T & 7) * 16 + (l & 15);
    int k = t * 32 + (l >> 4) * 8 + 2 * d;
    ws_u[OFF_WHHF + id] = packh2(w_hh[grow * HDIM + k], w_hh[grow * HDIM + k + 1]);
  } else if (id < 131072 + 65536) {      // wihf dwords: [q][T(32)][t(4)][l][d]
    int i2 = id - 131072;
    int q = i2 >> 15, T = (i2 >> 10) & 31, t = (i2 >> 8) & 3, l = (i2 >> 2) & 63, d = i2 & 3;
    int grow = (T >> 3) * 256 + q * 128 + (T & 7) * 16 + (l & 15);
    int k = t * 32 + (l >> 4) * 8 + 2 * d;
    ws_u[OFF_WIHF + i2] = packh2(w_ih[grow * EDIM + k], w_ih[grow * EDIM + k + 1]);
  } else if (id < 131072 + 65536 + HBUF_DW) {
    ws_u[OFF_HBUF + (id - 131072 - 65536)] = 0;   // zero seqs/payloads (incl. discovery slots)
  }
}

// ---------------- LSTM: 2-member clusters, 8-wave blocks, pairwise L2 exchange --------
// 16 clusters x 2 members = 32 blocks x 512 threads. Cluster c: batch cols 16c..16c+15.
// Member q (bid>>4): hidden units 128q..128q+127. Wave w (0..7) owns all 4 gates of
// units 16w+[0,16) of its member -> gate math stays lane-local.
// vs R6 (4-member): rendezvous partners 3->1, spin loads 6->2, own-half h-MFMA
// 2->4 k-tiles pre-spin (32 MFMA cover), peer-half 6->4 k-tiles post-detect.
// Exchange primitives byte-identical to R6 (proven): plain workgroup-scope 8B
// seqlock publish (stays in shared per-XCD L2) + agent-scope atomic poll; XCD
// discovery via HW_REG_XCC_ID; agent-scope store fallback if members split.
__global__ __launch_bounds__(512, 2) void lstm_kernel(
    const int* __restrict__ inp, const int* __restrict__ lengths,
    const float* __restrict__ h0, const float* __restrict__ c0,
    const float* __restrict__ emb,
    const float* __restrict__ b_ih, const float* __restrict__ b_hh,
    uint32* __restrict__ ws_u,
    float* __restrict__ outh, float* __restrict__ outc) {
  __shared__ uint32 x_l[2 * 16 * 68];   // [parity][b][64 dw + pad4]  x as f16 pairs
  __shared__ uint32 h_l[16 * 132];      // [b][128 dw + pad4]         h as f16 pairs
  __shared__ int fast_sh;

  const int tid  = threadIdx.x;
  const int lane = tid & 63, w = tid >> 6;     // wave 0..7
  const int c = blockIdx.x & 15, q = blockIdx.x >> 4;   // q in {0,1}
  const int n = lane & 15, p = lane >> 4;      // MFMA col / quad
  const int sb = tid >> 5, sk = tid & 31;      // staging map: col sb, sub sk

  uint64* hb = (uint64*)(ws_u + OFF_HBUF);

  // ---- same-XCD discovery via hbuf-embedded slots (R6-proven pattern) ----
  {
    uint32 xcc;
    asm volatile("s_getreg_b32 %0, hwreg(HW_REG_XCC_ID)" : "=s"(xcc));
    if (tid == 0) {
      int* sl = (int*)(ws_u + OFF_HBUF);
      const int sbase = (16 + c) * 4096;       // par=1, cluster c, b=0, dword units
      __hip_atomic_store(sl + sbase + 128 * q, (int)xcc + 1,
                         __ATOMIC_RELAXED, __HIP_MEMORY_SCOPE_AGENT);
      int v;
      do {
        v = __hip_atomic_load(sl + sbase + 128 * (1 - q),
                              __ATOMIC_RELAXED, __HIP_MEMORY_SCOPE_AGENT);
      } while (v == 0);
      fast_sh = (v == (int)xcc + 1);
    }
  }

  // ---- k-tile permutation: slots 0..3 = own member's h k-tiles (4q..4q+3) ----
  int perm[8];
#pragma unroll
  for (int i = 0; i < 8; ++i)
    perm[i] = (i < 4) ? (4 * q + i) : (4 * (1 - q) + (i - 4));
  int haddr[8];
#pragma unroll
  for (int i = 0; i < 8; ++i) haddr[i] = n * 132 + perm[i] * 16 + p * 4;

  // ---- weights: 48 NAMED register-resident A-fragments (AGPR-fed MFMA) ----
  const uint4* whhf = (const uint4*)(ws_u + OFF_WHHF);
  const uint4* wihf = (const uint4*)(ws_u + OFF_WIHF);
#define DECLW(g) uint4 ahh_##g##_0, ahh_##g##_1, ahh_##g##_2, ahh_##g##_3, \
                       ahh_##g##_4, ahh_##g##_5, ahh_##g##_6, ahh_##g##_7, \
                       aih_##g##_0, aih_##g##_1, aih_##g##_2, aih_##g##_3;
  DECLW(0) DECLW(1) DECLW(2) DECLW(3)
#define LOADW(g) { const int Tg = q * 32 + (g * 8 + w);                 \
    ahh_##g##_0 = whhf[(Tg * 8 + perm[0]) * 64 + lane];                 \
    ahh_##g##_1 = whhf[(Tg * 8 + perm[1]) * 64 + lane];                 \
    ahh_##g##_2 = whhf[(Tg * 8 + perm[2]) * 64 + lane];                 \
    ahh_##g##_3 = whhf[(Tg * 8 + perm[3]) * 64 + lane];                 \
    ahh_##g##_4 = whhf[(Tg * 8 + perm[4]) * 64 + lane];                 \
    ahh_##g##_5 = whhf[(Tg * 8 + perm[5]) * 64 + lane];                 \
    ahh_##g##_6 = whhf[(Tg * 8 + perm[6]) * 64 + lane];                 \
    ahh_##g##_7 = whhf[(Tg * 8 + perm[7]) * 64 + lane];                 \
    aih_##g##_0 = wihf[(Tg * 4 + 0) * 64 + lane];                       \
    aih_##g##_1 = wihf[(Tg * 4 + 1) * 64 + lane];                       \
    aih_##g##_2 = wihf[(Tg * 4 + 2) * 64 + lane];                       \
    aih_##g##_3 = wihf[(Tg * 4 + 3) * 64 + lane]; }
  LOADW(0) LOADW(1) LOADW(2) LOADW(3)

  // ---- per-lane epilogue state: units u = 16w+4p+r (member-local), col = 16c+n ----
  const int ub  = 16 * w + 4 * p;
  const int col = 16 * c + n;
  const int len = lengths[col] - 1;
  float bias_[4][4], cst[4];
#pragma unroll
  for (int g = 0; g < 4; ++g) {
    float4 bi = *(const float4*)(b_ih + g * 256 + q * 128 + ub);
    float4 bh = *(const float4*)(b_hh + g * 256 + q * 128 + ub);
    bias_[g][0] = bi.x + bh.x; bias_[g][1] = bi.y + bh.y;
    bias_[g][2] = bi.z + bh.z; bias_[g][3] = bi.w + bh.w;
  }
  {
    float4 cv = *(const float4*)(c0 + col * HDIM + q * 128 + ub);
    cst[0] = cv.x; cst[1] = cv.y; cst[2] = cv.z; cst[3] = cv.w;
  }

  // ---- prologue staging: h0 -> h_l (all 128 dw per col), x_0 -> x_l[0] ----
  {
    const float4* hsrc = (const float4*)(h0 + (16 * c + sb) * HDIM) + 2 * sk;
    float4 a0 = hsrc[0], a1 = hsrc[1];
    uint4 pk = { packh2(a0.x,a0.y), packh2(a0.z,a0.w), packh2(a1.x,a1.y), packh2(a1.z,a1.w) };
    *(uint4*)(h_l + sb * 132 + 4 * sk) = pk;
    int tok = inp[16 * c + sb];
    float4 v = ((const float4*)(emb + tok * EDIM))[sk];
    uint2 px = { packh2(v.x,v.y), packh2(v.z,v.w) };
    *(uint2*)(x_l + sb * 68 + 2 * sk) = px;
  }
  __syncthreads();
  const bool fast = (fast_sh != 0);

  // ---- spin chunk indices: peer region = chunks [64(1-q), 64(1-q)+64), 2/thread ----
  const int ch0 = 64 * (1 - q) + 2 * sk;

  for (int s = 0; s < S_LEN; ++s) {
    const int par = s & 1;

    // ---- C-issue: speculative peer chunk loads + next-token index hoist ----
    uint64 hv0 = 0, hv1 = 0;
    const uint64* rp = hb + (((par ^ 1) * 16 + c) * 16 + sb) * 128;
    if (s > 0) {
      hv0 = __hip_atomic_load(rp + ch0,     __ATOMIC_RELAXED, __HIP_MEMORY_SCOPE_AGENT);
      hv1 = __hip_atomic_load(rp + ch0 + 1, __ATOMIC_RELAXED, __HIP_MEMORY_SCOPE_AGENT);
    }
    int tok_next = 0;
    if (s + 1 < S_LEN) tok_next = inp[(s + 1) * BATCH + 16 * c + sb];

    // ---- x-MFMA (acc init = bias) + own-half h-MFMA (4 k-tiles): 32 MFMA cover ----
    f32x4 acc0 = { bias_[0][0], bias_[0][1], bias_[0][2], bias_[0][3] };
    f32x4 acc1 = { bias_[1][0], bias_[1][1], bias_[1][2], bias_[1][3] };
    f32x4 acc2 = { bias_[2][0], bias_[2][1], bias_[2][2], bias_[2][3] };
    f32x4 acc3 = { bias_[3][0], bias_[3][1], bias_[3][2], bias_[3][3] };
#define XMF(t) { uint4 xb = *(const uint4*)(x_l + par * 1088 + n * 68 + t * 16 + p * 4); \
    acc0 = MFMA16(aih_0_##t, xb, acc0); acc1 = MFMA16(aih_1_##t, xb, acc1);              \
    acc2 = MFMA16(aih_2_##t, xb, acc2); acc3 = MFMA16(aih_3_##t, xb, acc3); }
    XMF(0) XMF(1) XMF(2) XMF(3)
#define HMF(i) { uint4 hbv = *(const uint4*)(h_l + haddr[i]);                            \
    acc0 = MFMA16(ahh_0_##i, hbv, acc0); acc1 = MFMA16(ahh_1_##i, hbv, acc1);            \
    acc2 = MFMA16(ahh_2_##i, hbv, acc2); acc3 = MFMA16(ahh_3_##i, hbv, acc3); }
    HMF(0) HMF(1) HMF(2) HMF(3)      // own member's k-tiles (h_l own region, no comm)

    // ---- C-check: validate 2 seqs, spin-reload if stale; stage peer pair -> h_l ----
    if (s > 0) {
      const uint32 us = (uint32)s;
      while (!(((uint32)(hv0 >> 32) >= us) & ((uint32)(hv1 >> 32) >= us))) {
        hv0 = __hip_atomic_load(rp + ch0,     __ATOMIC_RELAXED, __HIP_MEMORY_SCOPE_AGENT);
        hv1 = __hip_atomic_load(rp + ch0 + 1, __ATOMIC_RELAXED, __HIP_MEMORY_SCOPE_AGENT);
      }
      *(uint2*)(h_l + sb * 132 + ch0) = (uint2){ (uint32)hv0, (uint32)hv1 };
    }
    __syncthreads();   // B2: h_l peer region complete

    // ---- emb gather for x_{s+1}: tok already resident; issue now, consume at G ----
    float4 xv = {0.f, 0.f, 0.f, 0.f};
    if (s + 1 < S_LEN) xv = ((const float4*)(emb + tok_next * EDIM))[sk];

    // ---- peer-half h-MFMA (4 k-tiles) ----
    HMF(4) HMF(5) HMF(6) HMF(7)

    // ---- gate math: fully lane-local (accG[r] = gate G of unit ub+r, col n) ----
    float hv4[4];
#pragma unroll
    for (int r = 0; r < 4; ++r) {
      float iv = sigf(acc0[r]), fv = sigf(acc1[r]);
      float gv = tanhfast(acc2[r]), ov = sigf(acc3[r]);
      float cn = fv * cst[r] + iv * gv;
      cst[r] = cn;
      hv4[r] = ov * tanhfast(cn);
    }

    // ---- G: publish 2 chunks first (critical path). Fast: plain 8B stores
    //      (stay in shared L2, R0/R6-proven visible to agent loads same-XCD).
    //      Slow: agent-scope stores (write-through, R2-proven cross-XCD). ----
    if (s + 1 < S_LEN) {
      uint32 pay0 = packh2(hv4[0], hv4[1]), pay1 = packh2(hv4[2], hv4[3]);
      const uint32 su = (uint32)(s + 1);
      const int P = 64 * q + 8 * w + 2 * p;          // member q's chunk pair
      uint64* wp = hb + (((par * 16 + c) * 16 + n) * 128 + P);
      uint64 pv0 = (uint64)pay0 | (((uint64)su) << 32);
      uint64 pv1 = (uint64)pay1 | (((uint64)su) << 32);
      if (fast) {
        __hip_atomic_store(wp,     pv0, __ATOMIC_RELAXED, __HIP_MEMORY_SCOPE_WORKGROUP);
        __hip_atomic_store(wp + 1, pv1, __ATOMIC_RELAXED, __HIP_MEMORY_SCOPE_WORKGROUP);
      } else {
        __hip_atomic_store(wp,     pv0, __ATOMIC_RELAXED, __HIP_MEMORY_SCOPE_AGENT);
        __hip_atomic_store(wp + 1, pv1, __ATOMIC_RELAXED, __HIP_MEMORY_SCOPE_AGENT);
      }
      *(uint2*)(h_l + n * 132 + P) = (uint2){ pay0, pay1 };
      uint2 px = { packh2(xv.x, xv.y), packh2(xv.z, xv.w) };
      *(uint2*)(x_l + (par ^ 1) * 1088 + sb * 68 + 2 * sk) = px;
    }
    if (s == len) {
      float4 ho = { hv4[0], hv4[1], hv4[2], hv4[3] };
      float4 co = { cst[0], cst[1], cst[2], cst[3] };
      *(float4*)(outh + col * HDIM + q * 128 + ub) = ho;
      *(float4*)(outc + col * HDIM + q * 128 + ub) = co;
    }
    __syncthreads();   // B4: h_l/x_l own-writes ordered before next step's reads
  }
}

// ---------------- decode: [B,2] = sigmoid(last_h @ dec_w^T) ----------------
__global__ __launch_bounds__(64) void decode_kernel(const float* __restrict__ outh,
                                                    const float* __restrict__ dec_w,
                                                    float* __restrict__ dec) {
  int b = blockIdx.x, l = threadIdx.x;
  float p0 = 0.f, p1 = 0.f;
#pragma unroll
  for (int m = 0; m < HDIM / 64; ++m) {
    float h = outh[b * HDIM + l + 64 * m];
    p0 = fmaf(h, dec_w[l + 64 * m], p0);
    p1 = fmaf(h, dec_w[HDIM + l + 64 * m], p1);
  }
#pragma unroll
  for (int off = 32; off > 0; off >>= 1) {
    p0 += __shfl_down(p0, off);
    p1 += __shfl_down(p1, off);
  }
  if (l == 0) {
    dec[b * ODIM + 0] = sigf(p0);
    dec[b * ODIM + 1] = sigf(p1);
  }
}

extern "C" void kernel_launch(void* const* d_in, const int* in_sizes, int n_in,
                              void* d_out, int out_size, void* d_ws, size_t ws_size,
                              hipStream_t stream) {
  const int*   inp     = (const int*)d_in[0];
  const int*   lengths = (const int*)d_in[1];
  const float* h0      = (const float*)d_in[2];
  const float* c0      = (const float*)d_in[3];
  const float* emb     = (const float*)d_in[4];
  const float* w_ih    = (const float*)d_in[5];
  const float* w_hh    = (const float*)d_in[6];
  const float* b_ih    = (const float*)d_in[7];
  const float* b_hh    = (const float*)d_in[8];
  const float* dec_w   = (const float*)d_in[9];

  uint32* ws_u = (uint32*)d_ws;

  float* dec  = (float*)d_out;           // [B, 2]
  float* outh = dec + BATCH * ODIM;      // [1, B, H]
  float* outc = outh + BATCH * HDIM;     // [1, B, H]

  const int prep_total = 131072 + 65536 + HBUF_DW;
  prep_kernel<<<(prep_total + 255) / 256, 256, 0, stream>>>(w_ih, w_hh, ws_u);
  lstm_kernel<<<32, 512, 0, stream>>>(inp, lengths, h0, c0, emb, b_ih, b_hh,
                                      ws_u, outh, outc);
  decode_kernel<<<BATCH, 64, 0, stream>>>(outh, dec_w, dec);
}

// Round 9
// 2389.922 us; speedup vs baseline: 1.5015x; 1.5015x over previous
//
#include <hip/hip_runtime.h>
#include <hip/hip_bf16.h>
#include <hip/hip_fp16.h>

// Problem: S,B,E,H,V,O = 1024,256,128,256,32000,2
#define S_LEN 1024
#define BATCH 256
#define EDIM  128
#define HDIM  256
#define ODIM  2

typedef unsigned int uint32;
typedef unsigned long long uint64;
typedef _Float16 half_t;
typedef half_t half2v __attribute__((ext_vector_type(2)));
typedef half_t half8  __attribute__((ext_vector_type(8)));
typedef float  f32x4  __attribute__((ext_vector_type(4)));

// ---------------- ws layout (uint32 units) ----------------
// whhf: MFMA A-fragments of W_hh, [4 q][16 T][8 t][64 lane][4 dw]  (f16 pairs)
// wihf: MFMA A-fragments of W_ih, [4 q][16 T][4 t][64 lane][4 dw]
// hbuf: LL chunks: [2 par][16 c][16 b][128 pair-chunks] x {payload dw, seq dw}
//       Discovery slots embedded in hbuf (par=1, c, b=0, chunk=32q) — prep-zeroed,
//       not overwritten until end of step 1, which happens-after discovery.
// done: clock-pin filler exit flag (prep-zeroed), own cache line after hbuf.
#define OFF_WHHF   0
#define OFF_WIHF   131072
#define OFF_HBUF   196608
#define HBUF_DW    131072   // 65536 chunks * 2 dw
#define OFF_DONE   327680   // 64 dwords reserved

__device__ __forceinline__ float sigf(float x)     { return 1.0f / (1.0f + __expf(-x)); }
__device__ __forceinline__ float tanhfast(float x) { return 1.0f - 2.0f / (__expf(2.0f * x) + 1.0f); }

__device__ __forceinline__ uint32 packh2(float a, float b) {
  union { uint32 u; half2v h; } c; c.h[0] = (half_t)a; c.h[1] = (half_t)b; return c.u;
}
__device__ __forceinline__ half8 as_h8(uint4 v) {
  union { uint4 u; half8 h; } c; c.u = v; return c.h;
}

// ---------------- prep: pack W into per-lane MFMA A-fragment order ----------------
// A-layout (16x16x32): lane l holds A[m = l&15][k = (l>>4)*8 + j], j=0..7 (f16 pairs, 4 dw).
// grow(T,l) = (T>>2)*256 + q*64 + (T&3)*16 + (l&15)  (gate g = T>>2, unit block tb = T&3).
__global__ void prep_kernel(const float* __restrict__ w_ih, const float* __restrict__ w_hh,
                            uint32* __restrict__ ws_u) {
  int id = blockIdx.x * 256 + threadIdx.x;
  if (id < 131072) {                     // whhf dwords: [q][T][t(8)][l][d]
    int q = id >> 15, T = (id >> 11) & 15, t = (id >> 8) & 7, l = (id >> 2) & 63, d = id & 3;
    int grow = (T >> 2) * 256 + q * 64 + (T & 3) * 16 + (l & 15);
    int k = t * 32 + (l >> 4) * 8 + 2 * d;
    ws_u[OFF_WHHF + id] = packh2(w_hh[grow * HDIM + k], w_hh[grow * HDIM + k + 1]);
  } else if (id < 131072 + 65536) {      // wihf dwords: [q][T][t(4)][l][d]
    int i2 = id - 131072;
    int q = i2 >> 14, T = (i2 >> 10) & 15, t = (i2 >> 8) & 3, l = (i2 >> 2) & 63, d = i2 & 3;
    int grow = (T >> 2) * 256 + q * 64 + (T & 3) * 16 + (l & 15);
    int k = t * 32 + (l >> 4) * 8 + 2 * d;
    ws_u[OFF_WIHF + i2] = packh2(w_ih[grow * EDIM + k], w_ih[grow * EDIM + k + 1]);
  } else if (id < 131072 + 65536 + HBUF_DW + 64) {
    ws_u[OFF_HBUF + (id - 131072 - 65536)] = 0;   // zero seqs/payloads + done flag
  }
}

// ---------------- LSTM: R6 structure (proven, 2414us) + clock-pin fillers ----------------
// Blocks 0..63: 16 clusters x 4 members, byte-identical protocol to R6 (seqlock
// exchange: plain workgroup-scope 8B publish staying in shared per-XCD L2 +
// agent-scope atomic polls; XCD discovery; agent-store fallback).
// Blocks 64..255: FMA spin on otherwise-idle CUs to hold DPM at boost clock.
// Rationale: R6's step period (~5660 "cycles" at nominal 2.4GHz) is ~4-5x the
// bounded protocol model (~1200cy) with only ~660cy busy -> suspected DPM
// downclock on a 3%-utilization kernel. Fillers raise chip utilization; real
// blocks' latency chain shrinks in wall time if clocks were the gap.
__global__ __launch_bounds__(256, 1) void lstm_kernel(
    const int* __restrict__ inp, const int* __restrict__ lengths,
    const float* __restrict__ h0, const float* __restrict__ c0,
    const float* __restrict__ emb,
    const float* __restrict__ b_ih, const float* __restrict__ b_hh,
    uint32* __restrict__ ws_u,
    float* __restrict__ outh, float* __restrict__ outc) {
  __shared__ uint32 x_l[2 * 16 * 68];   // [parity][b][64 dw + pad4]  x as f16 pairs
  __shared__ uint32 h_l[16 * 132];      // [b][128 dw + pad4]         h as f16 pairs
  __shared__ int fast_sh;

  const int tid = threadIdx.x;

  // ---- filler blocks: keep clocks up until real blocks finish ----
  if (blockIdx.x >= 64) {
    const int* done = (const int*)(ws_u + OFF_DONE);
    float a0 = (float)tid, a1 = a0 + 1.f, a2 = a0 + 2.f, a3 = a0 + 3.f;
    while (true) {
#pragma unroll
      for (int it = 0; it < 256; ++it) {
        a0 = fmaf(a0, 1.0000001f, 0.5f);
        a1 = fmaf(a1, 0.9999999f, 0.25f);
        a2 = fmaf(a2, 1.0000002f, 0.125f);
        a3 = fmaf(a3, 0.9999998f, 0.0625f);
      }
      asm volatile("" :: "v"(a0), "v"(a1), "v"(a2), "v"(a3));  // keep live (rule #17)
      if (__hip_atomic_load(done, __ATOMIC_RELAXED, __HIP_MEMORY_SCOPE_AGENT) != 0)
        return;
    }
  }

  const int lane = tid & 63, w = tid >> 6;     // wave 0..3
  const int c = blockIdx.x & 15, q = blockIdx.x >> 4;
  const int n = lane & 15, p = lane >> 4;      // MFMA col / quad
  const int sb = tid >> 4, j = tid & 15;       // staging map: col sb, sub j

  uint64* hb = (uint64*)(ws_u + OFF_HBUF);

  // ---- same-XCD discovery via hbuf-embedded slots (R6-proven) ----
  {
    uint32 xcc;
    asm volatile("s_getreg_b32 %0, hwreg(HW_REG_XCC_ID)" : "=s"(xcc));
    if (tid == 0) {
      int* sl = (int*)(ws_u + OFF_HBUF);
      const int sbase = (16 + c) * 4096;       // par=1, cluster c, b=0, dword units
      __hip_atomic_store(sl + sbase + 64 * q, (int)xcc + 1,
                         __ATOMIC_RELAXED, __HIP_MEMORY_SCOPE_AGENT);
      int ok = 1;
      for (int qq = 0; qq < 4; ++qq) {
        if (qq == q) continue;
        int v;
        do {
          v = __hip_atomic_load(sl + sbase + 64 * qq,
                                __ATOMIC_RELAXED, __HIP_MEMORY_SCOPE_AGENT);
        } while (v == 0);
        ok &= (v == (int)xcc + 1);
      }
      fast_sh = ok;
    }
  }

  // ---- own-t permutation: slots 0,1 = own member's k-tiles (2q, 2q+1) ----
  int perm[8];
  perm[0] = 2 * q; perm[1] = 2 * q + 1;
#pragma unroll
  for (int i = 2; i < 8; ++i) {
    int base = i - 2;
    perm[i] = base < 2 * q ? base : base + 2;
  }
  int haddr[8];
#pragma unroll
  for (int i = 0; i < 8; ++i) haddr[i] = n * 132 + perm[i] * 16 + p * 4;

  // ---- weights: all A-fragments register-resident (AGPR-fed MFMA, R7-verified) ----
  uint4 ahh[4][8], aih[4][4];
  {
    const uint4* whhf = (const uint4*)(ws_u + OFF_WHHF);
    const uint4* wihf = (const uint4*)(ws_u + OFF_WIHF);
#pragma unroll
    for (int g = 0; g < 4; ++g) {
      const int T = g * 4 + w;
#pragma unroll
      for (int i = 0; i < 8; ++i)
        ahh[g][i] = whhf[((q * 16 + T) * 8 + perm[i]) * 64 + lane];
#pragma unroll
      for (int t = 0; t < 4; ++t)
        aih[g][t] = wihf[((q * 16 + T) * 4 + t) * 64 + lane];
    }
  }

  // ---- per-lane epilogue state: units u = 16w+4p+r (r=0..3), col = 16c+n ----
  const int ub  = 16 * w + 4 * p;
  const int col = 16 * c + n;
  const int len = lengths[col] - 1;
  float bias_[4][4], cst[4];
#pragma unroll
  for (int g = 0; g < 4; ++g) {
    float4 bi = *(const float4*)(b_ih + g * 256 + q * 64 + ub);
    float4 bh = *(const float4*)(b_hh + g * 256 + q * 64 + ub);
    bias_[g][0] = bi.x + bh.x; bias_[g][1] = bi.y + bh.y;
    bias_[g][2] = bi.z + bh.z; bias_[g][3] = bi.w + bh.w;
  }
  {
    float4 cv = *(const float4*)(c0 + col * HDIM + q * 64 + ub);
    cst[0] = cv.x; cst[1] = cv.y; cst[2] = cv.z; cst[3] = cv.w;
  }

  // ---- prologue staging: h0 -> h_l (all 128 dw per col), x_0 -> x_l[0] ----
  {
    const float4* hsrc = (const float4*)(h0 + (16 * c + sb) * HDIM) + 4 * j;
    float4 a0 = hsrc[0], a1 = hsrc[1], a2 = hsrc[2], a3 = hsrc[3];
    uint4 pk0 = { packh2(a0.x,a0.y), packh2(a0.z,a0.w), packh2(a1.x,a1.y), packh2(a1.z,a1.w) };
    uint4 pk1 = { packh2(a2.x,a2.y), packh2(a2.z,a2.w), packh2(a3.x,a3.y), packh2(a3.z,a3.w) };
    *(uint4*)(h_l + sb * 132 + 8 * j)     = pk0;
    *(uint4*)(h_l + sb * 132 + 8 * j + 4) = pk1;
    int tok = inp[16 * c + sb];
    const float4* xsrc = (const float4*)(emb + tok * EDIM) + 2 * j;
    float4 v0 = xsrc[0], v1 = xsrc[1];
    uint4 px = { packh2(v0.x,v0.y), packh2(v0.z,v0.w), packh2(v1.x,v1.y), packh2(v1.z,v1.w) };
    *(uint4*)(x_l + sb * 68 + 4 * j) = px;
  }
  __syncthreads();
  const bool fast = (fast_sh != 0);

  // ---- staging chunk indices: 3 peer regions = [0,128) minus [32q, 32q+32) ----
  int ch[6];
#pragma unroll
  for (int i = 0; i < 6; ++i) {
    int idx6 = j * 6 + i;
    ch[i] = idx6 < q * 32 ? idx6 : idx6 + 32;
  }

  for (int s = 0; s < S_LEN; ++s) {
    const int par = s & 1;

    // ---- C-issue: speculative peer chunk loads (validated after MFMA cover) ----
    uint64 hv6[6] = {0, 0, 0, 0, 0, 0};
    const uint64* rp = hb + (((par ^ 1) * 16 + c) * 16 + sb) * 128;
    const uint64 *r0 = rp + ch[0], *r1 = rp + ch[1], *r2 = rp + ch[2],
                 *r3 = rp + ch[3], *r4 = rp + ch[4], *r5 = rp + ch[5];
    if (s > 0) {
      hv6[0] = __hip_atomic_load(r0, __ATOMIC_RELAXED, __HIP_MEMORY_SCOPE_AGENT);
      hv6[1] = __hip_atomic_load(r1, __ATOMIC_RELAXED, __HIP_MEMORY_SCOPE_AGENT);
      hv6[2] = __hip_atomic_load(r2, __ATOMIC_RELAXED, __HIP_MEMORY_SCOPE_AGENT);
      hv6[3] = __hip_atomic_load(r3, __ATOMIC_RELAXED, __HIP_MEMORY_SCOPE_AGENT);
      hv6[4] = __hip_atomic_load(r4, __ATOMIC_RELAXED, __HIP_MEMORY_SCOPE_AGENT);
      hv6[5] = __hip_atomic_load(r5, __ATOMIC_RELAXED, __HIP_MEMORY_SCOPE_AGENT);
    }
    int tok_next = 0;
    if (s + 1 < S_LEN) tok_next = inp[(s + 1) * BATCH + 16 * c + sb];

    // ---- x-MFMA (acc init = bias) + own-half h-MFMA: covers the spec loads ----
    f32x4 acc[4];
#pragma unroll
    for (int g = 0; g < 4; ++g)
      acc[g] = (f32x4){ bias_[g][0], bias_[g][1], bias_[g][2], bias_[g][3] };
#pragma unroll
    for (int t = 0; t < 4; ++t) {
      uint4 xb = *(const uint4*)(x_l + par * 1088 + n * 68 + t * 16 + p * 4);
#pragma unroll
      for (int g = 0; g < 4; ++g)
        acc[g] = __builtin_amdgcn_mfma_f32_16x16x32_f16(as_h8(aih[g][t]), as_h8(xb), acc[g], 0, 0, 0);
    }
#pragma unroll
    for (int i = 0; i < 2; ++i) {       // own member's k-tiles (h_l own region, no comm)
      uint4 hbv = *(const uint4*)(h_l + haddr[i]);
#pragma unroll
      for (int g = 0; g < 4; ++g)
        acc[g] = __builtin_amdgcn_mfma_f32_16x16x32_f16(as_h8(ahh[g][i]), as_h8(hbv), acc[g], 0, 0, 0);
    }

    // ---- C-check: validate seqs, spin-reload if stale; stage peers into h_l ----
    if (s > 0) {
      const uint32 us = (uint32)s;
      while (!(((uint32)(hv6[0] >> 32) >= us) & ((uint32)(hv6[1] >> 32) >= us) &
               ((uint32)(hv6[2] >> 32) >= us) & ((uint32)(hv6[3] >> 32) >= us) &
               ((uint32)(hv6[4] >> 32) >= us) & ((uint32)(hv6[5] >> 32) >= us))) {
        hv6[0] = __hip_atomic_load(r0, __ATOMIC_RELAXED, __HIP_MEMORY_SCOPE_AGENT);
        hv6[1] = __hip_atomic_load(r1, __ATOMIC_RELAXED, __HIP_MEMORY_SCOPE_AGENT);
        hv6[2] = __hip_atomic_load(r2, __ATOMIC_RELAXED, __HIP_MEMORY_SCOPE_AGENT);
        hv6[3] = __hip_atomic_load(r3, __ATOMIC_RELAXED, __HIP_MEMORY_SCOPE_AGENT);
        hv6[4] = __hip_atomic_load(r4, __ATOMIC_RELAXED, __HIP_MEMORY_SCOPE_AGENT);
        hv6[5] = __hip_atomic_load(r5, __ATOMIC_RELAXED, __HIP_MEMORY_SCOPE_AGENT);
      }
#pragma unroll
      for (int i = 0; i < 6; ++i) h_l[sb * 132 + ch[i]] = (uint32)hv6[i];
    }
    __syncthreads();   // B2: h_l peer regions complete

    // ---- emb gather for x_{s+1}: tok resident; issue now, consume at G ----
    float4 xv0 = {0.f,0.f,0.f,0.f}, xv1 = {0.f,0.f,0.f,0.f};
    if (s + 1 < S_LEN) {
      const float4* xsrc = (const float4*)(emb + tok_next * EDIM) + 2 * j;
      xv0 = xsrc[0]; xv1 = xsrc[1];
    }

    // ---- peer-half h-MFMA ----
#pragma unroll
    for (int i = 2; i < 8; ++i) {
      uint4 hbv = *(const uint4*)(h_l + haddr[i]);
#pragma unroll
      for (int g = 0; g < 4; ++g)
        acc[g] = __builtin_amdgcn_mfma_f32_16x16x32_f16(as_h8(ahh[g][i]), as_h8(hbv), acc[g], 0, 0, 0);
    }

    // ---- gate math: fully lane-local (acc[g][r] = gate g of unit ub+r, col n) ----
    float hv4[4];
#pragma unroll
    for (int r = 0; r < 4; ++r) {
      float iv = sigf(acc[0][r]), fv = sigf(acc[1][r]);
      float gv = tanhfast(acc[2][r]), ov = sigf(acc[3][r]);
      float cn = fv * cst[r] + iv * gv;
      cst[r] = cn;
      hv4[r] = ov * tanhfast(cn);
    }

    // ---- G: publish 2 chunks first (critical path). Fast: plain 8B stores
    //      (stay in shared L2, R0/R6-proven visible to agent loads same-XCD).
    //      Slow: agent-scope stores (write-through, R2-proven cross-XCD). ----
    if (s + 1 < S_LEN) {
      uint32 pay0 = packh2(hv4[0], hv4[1]), pay1 = packh2(hv4[2], hv4[3]);
      const uint32 su = (uint32)(s + 1);
      const int P = q * 32 + 8 * w + 2 * p;          // even -> 16B-aligned pair
      uint64* wp = hb + (((par * 16 + c) * 16 + n) * 128 + P);
      uint64 pv0 = (uint64)pay0 | (((uint64)su) << 32);
      uint64 pv1 = (uint64)pay1 | (((uint64)su) << 32);
      if (fast) {
        __hip_atomic_store(wp,     pv0, __ATOMIC_RELAXED, __HIP_MEMORY_SCOPE_WORKGROUP);
        __hip_atomic_store(wp + 1, pv1, __ATOMIC_RELAXED, __HIP_MEMORY_SCOPE_WORKGROUP);
      } else {
        __hip_atomic_store(wp,     pv0, __ATOMIC_RELAXED, __HIP_MEMORY_SCOPE_AGENT);
        __hip_atomic_store(wp + 1, pv1, __ATOMIC_RELAXED, __HIP_MEMORY_SCOPE_AGENT);
      }
      *(uint2*)(h_l + n * 132 + P) = (uint2){ pay0, pay1 };
      uint4 px = { packh2(xv0.x,xv0.y), packh2(xv0.z,xv0.w), packh2(xv1.x,xv1.y), packh2(xv1.z,xv1.w) };
      *(uint4*)(x_l + (par ^ 1) * 1088 + sb * 68 + 4 * j) = px;
    }
    if (s == len) {
      float4 ho = { hv4[0], hv4[1], hv4[2], hv4[3] };
      float4 co = { cst[0], cst[1], cst[2], cst[3] };
      *(float4*)(outh + col * HDIM + q * 64 + ub) = ho;
      *(float4*)(outc + col * HDIM + q * 64 + ub) = co;
    }
    __syncthreads();   // B4: h_l/x_l own-writes ordered before next step's reads
  }

  // ---- release the clock-pin fillers ----
  if (blockIdx.x == 0 && tid == 0)
    __hip_atomic_store((int*)(ws_u + OFF_DONE), 1,
                       __ATOMIC_RELAXED, __HIP_MEMORY_SCOPE_AGENT);
}

// ---------------- decode: [B,2] = sigmoid(last_h @ dec_w^T) ----------------
__global__ __launch_bounds__(64) void decode_kernel(const float* __restrict__ outh,
                                                    const float* __restrict__ dec_w,
                                                    float* __restrict__ dec) {
  int b = blockIdx.x, l = threadIdx.x;
  float p0 = 0.f, p1 = 0.f;
#pragma unroll
  for (int m = 0; m < HDIM / 64; ++m) {
    float h = outh[b * HDIM + l + 64 * m];
    p0 = fmaf(h, dec_w[l + 64 * m], p0);
    p1 = fmaf(h, dec_w[HDIM + l + 64 * m], p1);
  }
#pragma unroll
  for (int off = 32; off > 0; off >>= 1) {
    p0 += __shfl_down(p0, off);
    p1 += __shfl_down(p1, off);
  }
  if (l == 0) {
    dec[b * ODIM + 0] = sigf(p0);
    dec[b * ODIM + 1] = sigf(p1);
  }
}

extern "C" void kernel_launch(void* const* d_in, const int* in_sizes, int n_in,
                              void* d_out, int out_size, void* d_ws, size_t ws_size,
                              hipStream_t stream) {
  const int*   inp     = (const int*)d_in[0];
  const int*   lengths = (const int*)d_in[1];
  const float* h0      = (const float*)d_in[2];
  const float* c0      = (const float*)d_in[3];
  const float* emb     = (const float*)d_in[4];
  const float* w_ih    = (const float*)d_in[5];
  const float* w_hh    = (const float*)d_in[6];
  const float* b_ih    = (const float*)d_in[7];
  const float* b_hh    = (const float*)d_in[8];
  const float* dec_w   = (const float*)d_in[9];

  uint32* ws_u = (uint32*)d_ws;

  float* dec  = (float*)d_out;           // [B, 2]
  float* outh = dec + BATCH * ODIM;      // [1, B, H]
  float* outc = outh + BATCH * HDIM;     // [1, B, H]

  const int prep_total = 131072 + 65536 + HBUF_DW + 64;
  prep_kernel<<<(prep_total + 255) / 256, 256, 0, stream>>>(w_ih, w_hh, ws_u);
  lstm_kernel<<<256, 256, 0, stream>>>(inp, lengths, h0, c0, emb, b_ih, b_hh,
                                       ws_u, outh, outc);
  decode_kernel<<<BATCH, 64, 0, stream>>>(outh, dec_w, dec);
}